// Round 4
// baseline (333.665 us; speedup 1.0000x reference)
//
#include <hip/hip_runtime.h>

namespace {
constexpr int Bn = 16, Hn = 512, Wn = 512;
constexpr int HW  = Hn * Wn;        // 262144
constexpr int CHW = 8 * HW;         // 2097152
constexpr int NCOL = Bn * Wn;       // 8192 dice columns
constexpr int WALK = 8;             // rows walked per thread
constexpr int GX   = Hn / WALK;     // 64
constexpr int NBLK = GX * Bn;       // 1024 blocks
constexpr int SLABN = NBLK * 512;   // 524,288 floats per partial table
constexpr int FBLK  = 32;           // fallback finisher blocks
constexpr int FBLK2 = 256;          // slab finisher blocks (4 bscal slots each)

constexpr float L2E  = 1.4426950408889634f;   // log2(e)
constexpr float LN2  = 0.6931471805599453f;
constexpr float CLMP = -144.26950408889634f;  // -100 / ln2 (clamp in log2 units)

__device__ __forceinline__ float frcp(float x) { return __builtin_amdgcn_rcpf(x); }
#if __has_builtin(__builtin_amdgcn_exp2f)
__device__ __forceinline__ float fexp2(float x) { return __builtin_amdgcn_exp2f(x); }
#else
__device__ __forceinline__ float fexp2(float x) { return exp2f(x); }
#endif
#if __has_builtin(__builtin_amdgcn_logf)
__device__ __forceinline__ float flog2(float x) { return __builtin_amdgcn_logf(x); }
#else
__device__ __forceinline__ float flog2(float x) { return log2f(x); }
#endif
} // namespace

// n[c](h,w) = sigmoid(c_map[c][h+DY[c]][w+DX[c]]), zero outside image.
// vote[i] = p[i] * n[7-i].  DX = {1,0,-1,1,-1,1,0,-1}, DY = {1,1,1,0,0,-1,-1,-1}.
// BCE sums in log2 units via log-of-product fusion; one x ln2 at bscal write.
//
// R4: demand-byte reduction, theory-discriminating. R0/R2/R3 nulls (occ 19-55%,
// 8B vs 16B lanes, 1-row prefetch, FETCH -17%) imply delivered-read-BW wall
// ~3.0 TB/s (= read half of m13's 6.29 copy). Levers left are bytes only:
//  (a) WALK 4->8: stripe halo (6 ch-rows) amortized over 8 rows, c_map demand
//      159->146 MB;
//  (b) neighbor values via __shfl_up/down(1) of already-computed sigmoids
//      instead of 6 half-wasted 4B/lane boundary loads per row; only lanes
//      0/63 keep a predicated scalar load (1 line vs 4 per instr).
// Tripwire: WRITE_SIZE must be ~6.3 MB (slab halved); >8 MB = spill -> revert.

struct Row {
    float2 a3, a4, a5, a6, a7;   // row h, ch3-7
    float2 f0, f1, f2;           // row h+1, ch0-2
    float  b0, b2, b3, b4, b5, b7;  // boundary scalars (lanes 0/63 only)
    int2   t;                    // target row h
    int2   u0, u1, u2, u3, u4, u5, u6, u7;  // con_target row h
};

template <bool SLAB>
__global__ __launch_bounds__(256) void bicon_main(
    const float* __restrict__ c_map,
    const int*   __restrict__ target,
    const int*   __restrict__ con_target,
    float* __restrict__ col_i, float* __restrict__ col_j, float* __restrict__ col_x,
    double* __restrict__ bscal)
{
    const int tid  = threadIdx.x;        // 0..255
    const int lane = tid & 63;
    const int wv   = tid >> 6;           // 0..3 = column quarter

    // Bijective XCD-chunk swizzle (NBLK % 8 == 0): each XCD owns 128
    // consecutive work ids = 2 full batch-rows of gx stripes.
    const int hwid = blockIdx.y * GX + blockIdx.x;
    const int work = (hwid & 7) * (NBLK / 8) + (hwid >> 3);
    const int gx   = work & (GX - 1);
    const int b    = work >> 6;          // work / GX

    const int hstart = gx * WALK;
    const int wq   = wv * 128 + lane * 2;   // first of this lane's 2 columns

    const float* cm = c_map      + (size_t)b * CHW;
    const int*   ct = con_target + (size_t)b * CHW;
    const int*   tg = target     + (size_t)b * HW;

    float s_con = 0.f, s_bi = 0.f, s_bce = 0.f, s_dec = 0.f;   // log2 units
    float ci[2] = {0, 0}, cj[2] = {0, 0}, cx[2] = {0, 0};

    auto sig2 = [&](const float2& v, float s[2]) {
        s[0] = frcp(1.f + fexp2(-v.x * L2E));
        s[1] = frcp(1.f + fexp2(-v.y * L2E));
    };

    const bool lnR = (lane == 63);   // right boundary lane of this wave
    const bool lnL = (lane == 0);    // left boundary lane

    auto issue = [&](int hh, Row& R) {
        const int bs = hh * Wn + wq;
        R.a3 = *(const float2*)(cm + 3 * HW + bs);
        R.a4 = *(const float2*)(cm + 4 * HW + bs);
        R.a5 = *(const float2*)(cm + 5 * HW + bs);
        R.a6 = *(const float2*)(cm + 6 * HW + bs);
        R.a7 = *(const float2*)(cm + 7 * HW + bs);
        R.f0 = *(const float2*)(cm + 0 * HW + bs + Wn);
        R.f1 = *(const float2*)(cm + 1 * HW + bs + Wn);
        R.f2 = *(const float2*)(cm + 2 * HW + bs + Wn);
        // boundary scalars: only the lane that uses them loads (1 line/instr)
        R.b0 = lnR ? cm[0 * HW + bs + Wn + 2] : 0.f;
        R.b3 = lnR ? cm[3 * HW + bs + 2]      : 0.f;
        R.b5 = lnR ? cm[5 * HW + bs - Wn + 2] : 0.f;
        R.b2 = lnL ? cm[2 * HW + bs + Wn - 1] : 0.f;
        R.b4 = lnL ? cm[4 * HW + bs - 1]      : 0.f;
        R.b7 = lnL ? cm[7 * HW + bs - Wn - 1] : 0.f;
        R.t  = *(const int2*)(tg + bs);
        R.u0 = *(const int2*)(ct + 0 * HW + bs);
        R.u1 = *(const int2*)(ct + 1 * HW + bs);
        R.u2 = *(const int2*)(ct + 2 * HW + bs);
        R.u3 = *(const int2*)(ct + 3 * HW + bs);
        R.u4 = *(const int2*)(ct + 4 * HW + bs);
        R.u5 = *(const int2*)(ct + 5 * HW + bs);
        R.u6 = *(const int2*)(ct + 6 * HW + bs);
        R.u7 = *(const int2*)(ct + 7 * HW + bs);
    };

    // ---- kick off row hstart loads FIRST ----
    Row cu, nx;
    issue(hstart, cu);

    // ---- carried window: sigma(ch0..2)@h, sigma(ch5..7)@h-1 ----
    float C0[2], C1[2], C2[2], P5[2], P6[2], P7[2];
    {
        const int pb = hstart * Wn + wq;
        sig2(*(const float2*)(cm + 0 * HW + pb), C0);
        sig2(*(const float2*)(cm + 1 * HW + pb), C1);
        sig2(*(const float2*)(cm + 2 * HW + pb), C2);
    }
    if (hstart > 0) {   // block-uniform
        const int pb = (hstart - 1) * Wn + wq;
        sig2(*(const float2*)(cm + 5 * HW + pb), P5);
        sig2(*(const float2*)(cm + 6 * HW + pb), P6);
        sig2(*(const float2*)(cm + 7 * HW + pb), P7);
    } else {
#pragma unroll
        for (int k = 0; k < 2; ++k) { P5[k] = 0.f; P6[k] = 0.f; P7[k] = 0.f; }
    }

    const bool edR = (wq + 2 == Wn);   // true only for wv3 lane63
    const bool edL = (wq == 0);        // true only for wv0 lane0

#pragma unroll
    for (int r = 0; r < WALK; ++r) {
        const int  h     = hstart + r;
        const bool hasDn = (h + 1 < Hn);
        const bool hasUp = (h > 0);

        // ---- prefetch next row before touching cu (compile-time guard) ----
        if (r + 1 < WALK) issue(h + 1, nx);

        // ---- con bits ----
        unsigned lo = 0u;
        auto mix = [&](const int2& u, int c) {
            lo |= ((unsigned)u.x << c) | ((unsigned)u.y << (8 + c));
        };
        mix(cu.u0, 0); mix(cu.u1, 1); mix(cu.u2, 2); mix(cu.u3, 3);
        mix(cu.u4, 4); mix(cu.u5, 5); mix(cu.u6, 6); mix(cu.u7, 7);

        // ---- fresh centers ch3-7: sigma + conmap d-product accumulation ----
        float dp[2] = {1.f, 1.f};   // prod of d over ch3..7
        float ys[2] = {0.f, 0.f};   // sum of y where bit==0
        float c3[2], c4[2], c5[2], c6[2], c7[2];
        auto fresh = [&](int c, const float2& v, float s[2]) {
            const float xs[2] = {v.x, v.y};
#pragma unroll
            for (int k = 0; k < 2; ++k) {
                const float y = xs[k] * L2E;
                const float e = fexp2(-y);
                const float d = 1.f + e;
                s[k] = frcp(d);
                dp[k] *= d;
                ys[k] += ((lo >> (8 * k + c)) & 1u) ? 0.f : y;
            }
        };
        fresh(3, cu.a3, c3); fresh(4, cu.a4, c4); fresh(5, cu.a5, c5);
        fresh(6, cu.a6, c6); fresh(7, cu.a7, c7);

        // ---- conmap: carried ch0-2 select-product + ch3-7 d-form ----
#pragma unroll
        for (int k = 0; k < 2; ++k) {
            const float q0 = ((lo >> (8 * k + 0)) & 1u) ? C0[k] : 1.f - C0[k];
            const float q1 = ((lo >> (8 * k + 1)) & 1u) ? C1[k] : 1.f - C1[k];
            const float q2 = ((lo >> (8 * k + 2)) & 1u) ? C2[k] : 1.f - C2[k];
            s_con += flog2(q0 * q1 * q2) - flog2(dp[k]) - ys[k];
        }

        // ---- next-row sigmas ----
        float F0[2], F1[2], F2[2];
        sig2(cu.f0, F0); sig2(cu.f1, F1); sig2(cu.f2, F2);

        // ---- neighbor values: lane shuffle of already-computed sigmoids;
        //      boundary lanes (0/63) fall back to scalar-load sigmoids ----
        const float r0 = __shfl_down(F0[0], 1);
        const float r3 = __shfl_down(c3[0], 1);
        const float r5 = __shfl_down(P5[0], 1);
        const float l2 = __shfl_up(F2[1], 1);
        const float l4 = __shfl_up(c4[1], 1);
        const float l7 = __shfl_up(P7[1], 1);
        const float s0b = frcp(1.f + fexp2(-cu.b0 * L2E));
        const float s2b = frcp(1.f + fexp2(-cu.b2 * L2E));
        const float s3b = frcp(1.f + fexp2(-cu.b3 * L2E));
        const float s4b = frcp(1.f + fexp2(-cu.b4 * L2E));
        const float s5b = frcp(1.f + fexp2(-cu.b5 * L2E));
        const float s7b = frcp(1.f + fexp2(-cu.b7 * L2E));

        // ---- neighbor arrays n[c] (masked shifts) ----
        float n0[2], n1[2], n2[2], n3[2], n4[2], n5[2], n6[2], n7[2];
        n0[0] = F0[1]; n3[0] = c3[1]; n5[0] = P5[1];
        n2[1] = F2[0]; n4[1] = c4[0]; n7[1] = P7[0];
        n0[1] = edR ? 0.f : (lnR ? s0b : r0);
        n3[1] = edR ? 0.f : (lnR ? s3b : r3);
        n5[1] = edR ? 0.f : (lnR ? s5b : r5);
        n2[0] = edL ? 0.f : (lnL ? s2b : l2);
        n4[0] = edL ? 0.f : (lnL ? s4b : l4);
        n7[0] = edL ? 0.f : (lnL ? s7b : l7);
#pragma unroll
        for (int k = 0; k < 2; ++k) {
            n1[k] = hasDn ? F1[k] : 0.f;
            n6[k] = hasUp ? P6[k] : 0.f;
            if (!hasDn) { n0[k] = 0.f; n2[k] = 0.f; }
            if (!hasUp) { n5[k] = 0.f; n7[k] = 0.f; }
        }

        // ---- votes + bimap product accumulation ----
        float vmax[2] = {0.f, 0.f}, vmin[2] = {2.f, 2.f};
        float pr[2]   = {1.f, 1.f};
        float zc[2]   = {0.f, 0.f};   // count of bit=1 zero-votes
        auto vote = [&](int i, const float p[2], const float n[2]) {
#pragma unroll
            for (int k = 0; k < 2; ++k) {
                const float v = p[k] * n[k];
                vmax[k] = fmaxf(vmax[k], v);
                vmin[k] = fminf(vmin[k], v);
                const bool bit = (lo >> (8 * k + i)) & 1u;
                const bool z   = bit && (v == 0.f);     // only from masked edges
                float sel = bit ? v : 1.f - v;
                sel = z ? 1.f : sel;
                zc[k] += z ? 1.f : 0.f;
                pr[k] *= sel;
            }
        };
        vote(0, C0, n7); vote(1, C1, n6); vote(2, C2, n5); vote(3, c3, n4);
#pragma unroll
        for (int k = 0; k < 2; ++k) { s_bi += flog2(pr[k]); pr[k] = 1.f; }
        vote(4, c4, n3); vote(5, c5, n2); vote(6, c6, n1); vote(7, c7, n0);
#pragma unroll
        for (int k = 0; k < 2; ++k) { s_bi += flog2(pr[k]) + CLMP * zc[k]; }

        // ---- per-pixel tail ----
        const int tk[2] = {cu.t.x, cu.t.y};
#pragma unroll
        for (int k = 0; k < 2; ++k) {
            const float fm = vmax[k];
            s_bce += fmaxf(flog2(tk[k] ? fm : 1.f - fm), CLMP);
            const int sc = __popc((int)((lo >> (8 * k)) & 0xffu));
            s_dec += (sc > 0 && sc < 8) ? fmaxf(flog2(1.f - vmin[k]), CLMP) : 0.f;
            ci[k] += (float)tk[k];
            cj[k] += fm;
            cx[k] += tk[k] ? fm : 0.f;
        }

        // ---- rotate window + pipeline ----
#pragma unroll
        for (int k = 0; k < 2; ++k) {
            C0[k] = F0[k]; C1[k] = F1[k]; C2[k] = F2[k];
            P5[k] = c5[k]; P6[k] = c6[k]; P7[k] = c7[k];
        }
        if (r + 1 < WALK) cu = nx;
    }

    // ---- dice partials: thread-exclusive columns, direct store ----
    if constexpr (SLAB) {
        const size_t sb = ((size_t)work) << 9;
        float2 vi; vi.x = ci[0]; vi.y = ci[1];
        float2 vj; vj.x = cj[0]; vj.y = cj[1];
        float2 vx; vx.x = cx[0]; vx.y = cx[1];
        *(float2*)(col_i + sb + wq) = vi;
        *(float2*)(col_j + sb + wq) = vj;
        *(float2*)(col_x + sb + wq) = vx;
    } else {
#pragma unroll
        for (int k = 0; k < 2; ++k) {
            atomicAdd(&col_i[b * Wn + wq + k], ci[k]);
            atomicAdd(&col_j[b * Wn + wq + k], cj[k]);
            atomicAdd(&col_x[b * Wn + wq + k], cx[k]);
        }
    }

    // ---- scalar sums: wave shuffle reduction ----
#pragma unroll
    for (int off = 32; off > 0; off >>= 1) {
        s_con += __shfl_down(s_con, off);
        s_bi  += __shfl_down(s_bi,  off);
        s_bce += __shfl_down(s_bce, off);
        s_dec += __shfl_down(s_dec, off);
    }
    __shared__ float wred[4][4];
    if (lane == 0) {   // convert log2 -> ln units here (one mul per sum)
        wred[wv][0] = s_con * LN2; wred[wv][1] = s_bi * LN2;
        wred[wv][2] = s_bce * LN2; wred[wv][3] = s_dec * LN2;
    }
    __syncthreads();
    if (tid < 4) {
        bscal[(size_t)work * 4 + tid] =
            (double)(wred[0][tid] + wred[1][tid] + wred[2][tid] + wred[3][tid]);
    }
}

// Slab finisher: 256 blocks x 256 threads. Block bx owns 32 columns; each
// column's 64 gx-partials are summed by 8 threads (8 each) -> LDS -> lane.
__global__ __launch_bounds__(256) void bicon_finish_slab(
    const float* __restrict__ pI,
    const float* __restrict__ pJ,
    const float* __restrict__ pX,
    const double* __restrict__ bscal,
    float* __restrict__ out)
{
    const int tid = threadIdx.x;
    const int w32 = tid & 31;                 // which of the block's 32 columns
    const int p   = tid >> 5;                 // gx partition 0..7 (8 gx each)
    const int col = blockIdx.x * 32 + w32;    // 0..8191
    const int b   = col >> 9;
    const int w   = col & 511;

    float fi = 0.f, fj = 0.f, fx = 0.f;
    const size_t base = (((size_t)(b * GX + p * 8)) << 9) + w;
#pragma unroll
    for (int g = 0; g < 8; ++g) {
        const size_t idx = base + ((size_t)g << 9);
        fi += pI[idx]; fj += pJ[idx]; fx += pX[idx];
    }
    __shared__ float red[3][8][32];           // 3 KB
    red[0][p][w32] = fi; red[1][p][w32] = fj; red[2][p][w32] = fx;
    __syncthreads();

    double part = 0.0;
    if (tid < 32) {                           // dice term for 32 columns
        float si = 0.f, sj = 0.f, sx = 0.f;
#pragma unroll
        for (int q = 0; q < 8; ++q) {
            si += red[0][q][tid]; sj += red[1][q][tid]; sx += red[2][q][tid];
        }
        part = (1.0 - (2.0 * (double)sx + 0.001) /
                      ((double)si + (double)sj + 0.001)) / 8192.0;
    }
    if (tid >= 64 && tid < 68) {              // 4 bscal slots, on wave 1
        const int s = blockIdx.x * 4 + (tid - 64);
        const double c0 = bscal[s * 4 + 0], c1 = bscal[s * 4 + 1];
        const double c2 = bscal[s * 4 + 2], c3 = bscal[s * 4 + 3];
        part += -0.8 * c0 / 33554432.0 - 0.2 * c1 / 33554432.0
                - c2 / 4194304.0 - c3 / 4194304.0;
    }
#pragma unroll
    for (int off = 32; off > 0; off >>= 1) part += __shfl_down(part, off);
    __shared__ double red2[4];
    if ((tid & 63) == 0) red2[tid >> 6] = part;
    __syncthreads();
    if (tid == 0) atomicAdd(out, (float)(red2[0] + red2[1] + red2[2] + red2[3]));
}

// Fallback finisher (atomic path): cols already reduced, 32 blocks suffice.
__global__ __launch_bounds__(256) void bicon_finish(
    const float* __restrict__ col_i,
    const float* __restrict__ col_j,
    const float* __restrict__ col_x,
    const double* __restrict__ bscal,
    float* __restrict__ out)
{
    const int tid = threadIdx.x;
    const int col = blockIdx.x * 256 + tid;      // exactly NCOL threads total

    double part;
    {
        const float fi = col_i[col], fj = col_j[col], fx = col_x[col];
        part = (1.0 - (2.0 * (double)fx + 0.001) /
                      ((double)fi + (double)fj + 0.001)) / 8192.0;
    }
    if (tid < 32) {   // 32 bscal slots per block: 32 blocks * 32 = 1024 = NBLK
        const int s = blockIdx.x * 32 + tid;
        const double c0 = bscal[s * 4 + 0], c1 = bscal[s * 4 + 1];
        const double c2 = bscal[s * 4 + 2], c3 = bscal[s * 4 + 3];
        part += -0.8 * c0 / 33554432.0 - 0.2 * c1 / 33554432.0
                - c2 / 4194304.0 - c3 / 4194304.0;
    }
#pragma unroll
    for (int off = 32; off > 0; off >>= 1) part += __shfl_down(part, off);
    __shared__ double red[4];
    if ((tid & 63) == 0) red[tid >> 6] = part;
    __syncthreads();
    if (tid == 0) atomicAdd(out, (float)(red[0] + red[1] + red[2] + red[3]));
}

extern "C" void kernel_launch(void* const* d_in, const int* in_sizes, int n_in,
                              void* d_out, int out_size, void* d_ws, size_t ws_size,
                              hipStream_t stream) {
    const float* c_map      = (const float*)d_in[0];
    const int*   target     = (const int*)d_in[1];
    const int*   con_target = (const int*)d_in[2];
    float* out = (float*)d_out;

    char* ws = (char*)d_ws;
    const size_t slab_need = (size_t)3 * SLABN * sizeof(float)
                           + (size_t)NBLK * 4 * sizeof(double);   // ~6.33 MB

    dim3 grid(GX, Bn);       // 64 x 16 = 1024 blocks
    dim3 block(256);

    hipMemsetAsync(d_out, 0, sizeof(float), stream);  // finisher atomics here

    if (ws_size >= slab_need) {
        float*  pI    = (float*)ws;                   // 1024 x 512 partials
        float*  pJ    = pI + SLABN;
        float*  pX    = pJ + SLABN;
        double* bscal = (double*)(ws + (size_t)3 * SLABN * sizeof(float));
        // no col memset needed: slabs are fully written
        bicon_main<true><<<grid, block, 0, stream>>>(c_map, target, con_target,
                                                     pI, pJ, pX, bscal);
        bicon_finish_slab<<<FBLK2, 256, 0, stream>>>(pI, pJ, pX, bscal, out);
    } else {
        float*  col_i = (float*)ws;                               // 8192 floats
        float*  col_j = col_i + NCOL;
        float*  col_x = col_j + NCOL;
        double* bscal = (double*)(ws + 3 * NCOL * sizeof(float)); // 1024*4 doubles
        hipMemsetAsync(d_ws, 0, 3 * NCOL * sizeof(float), stream);
        bicon_main<false><<<grid, block, 0, stream>>>(c_map, target, con_target,
                                                      col_i, col_j, col_x, bscal);
        bicon_finish<<<FBLK, 256, 0, stream>>>(col_i, col_j, col_x, bscal, out);
    }
}

// Round 5
// 306.454 us; speedup vs baseline: 1.0888x; 1.0888x over previous
//
#include <hip/hip_runtime.h>

namespace {
constexpr int Bn = 16, Hn = 512, Wn = 512;
constexpr int HW  = Hn * Wn;        // 262144
constexpr int CHW = 8 * HW;         // 2097152
constexpr int NCOL = Bn * Wn;       // 8192 dice columns
constexpr int WALK = 8;             // rows walked per thread
constexpr int GX   = Hn / WALK;     // 64
constexpr int NBLK = GX * Bn;       // 1024 blocks
constexpr int SLABN = NBLK * 512;   // 524,288 floats per partial table
constexpr int FBLK  = 32;           // fallback finisher blocks
constexpr int FBLK2 = 256;          // slab finisher blocks (4 bscal slots each)

constexpr float L2E  = 1.4426950408889634f;   // log2(e)
constexpr float LN2  = 0.6931471805599453f;
constexpr float CLMP = -144.26950408889634f;  // -100 / ln2 (clamp in log2 units)

__device__ __forceinline__ float frcp(float x) { return __builtin_amdgcn_rcpf(x); }
#if __has_builtin(__builtin_amdgcn_exp2f)
__device__ __forceinline__ float fexp2(float x) { return __builtin_amdgcn_exp2f(x); }
#else
__device__ __forceinline__ float fexp2(float x) { return exp2f(x); }
#endif
#if __has_builtin(__builtin_amdgcn_logf)
__device__ __forceinline__ float flog2(float x) { return __builtin_amdgcn_logf(x); }
#else
__device__ __forceinline__ float flog2(float x) { return log2f(x); }
#endif
} // namespace

// n[c](h,w) = sigmoid(c_map[c][h+DY[c]][w+DX[c]]), zero outside image.
// vote[i] = p[i] * n[7-i].  DX = {1,0,-1,1,-1,1,0,-1}, DY = {1,1,1,0,0,-1,-1,-1}.
// BCE sums in log2 units via log-of-product fusion; one x ln2 at bscal write.
//
// R5: R4's demand-byte cuts (WALK=8 halo amortization + shuffle-neighbors)
// WITHOUT R4's register cost. R4's full unroll hit VGPR 220 -> occ 10.7% ->
// latency-bound regression (145us). Here the row body is a lambda and the
// loop is a rolled ping-pong over two Row buffers with COMPILE-TIME roles
// (2 rows/iter, no dynamic indexing, no struct copies) -> ~130 VGPR at any
// WALK, 1-row prefetch depth preserved.
// Model under test: dur = L1-demand bytes / 2.84 TB/s (297 MB -> ~105us).
// Tripwires: VGPR>170 or WRITE_SIZE>8MB -> revert.

struct Row {
    float2 a3, a4, a5, a6, a7;   // row h, ch3-7
    float2 f0, f1, f2;           // row h+1, ch0-2
    float  b0, b2, b3, b4, b5, b7;  // boundary scalars (lanes 0/63 only)
    int2   t;                    // target row h
    int2   u0, u1, u2, u3, u4, u5, u6, u7;  // con_target row h
};

template <bool SLAB>
__global__ __launch_bounds__(256) void bicon_main(
    const float* __restrict__ c_map,
    const int*   __restrict__ target,
    const int*   __restrict__ con_target,
    float* __restrict__ col_i, float* __restrict__ col_j, float* __restrict__ col_x,
    double* __restrict__ bscal)
{
    const int tid  = threadIdx.x;        // 0..255
    const int lane = tid & 63;
    const int wv   = tid >> 6;           // 0..3 = column quarter

    // Bijective XCD-chunk swizzle (NBLK % 8 == 0): each XCD owns 128
    // consecutive work ids = 2 full batch-rows of gx stripes.
    const int hwid = blockIdx.y * GX + blockIdx.x;
    const int work = (hwid & 7) * (NBLK / 8) + (hwid >> 3);
    const int gx   = work & (GX - 1);
    const int b    = work >> 6;          // work / GX

    const int hstart = gx * WALK;
    const int wq   = wv * 128 + lane * 2;   // first of this lane's 2 columns

    const float* cm = c_map      + (size_t)b * CHW;
    const int*   ct = con_target + (size_t)b * CHW;
    const int*   tg = target     + (size_t)b * HW;

    float s_con = 0.f, s_bi = 0.f, s_bce = 0.f, s_dec = 0.f;   // log2 units
    float ci[2] = {0, 0}, cj[2] = {0, 0}, cx[2] = {0, 0};

    auto sig2 = [&](const float2& v, float s[2]) {
        s[0] = frcp(1.f + fexp2(-v.x * L2E));
        s[1] = frcp(1.f + fexp2(-v.y * L2E));
    };

    const bool lnR = (lane == 63);   // right boundary lane of this wave
    const bool lnL = (lane == 0);    // left boundary lane

    auto issue = [&](int hh, Row& R) {
        const int bs = hh * Wn + wq;
        R.a3 = *(const float2*)(cm + 3 * HW + bs);
        R.a4 = *(const float2*)(cm + 4 * HW + bs);
        R.a5 = *(const float2*)(cm + 5 * HW + bs);
        R.a6 = *(const float2*)(cm + 6 * HW + bs);
        R.a7 = *(const float2*)(cm + 7 * HW + bs);
        R.f0 = *(const float2*)(cm + 0 * HW + bs + Wn);
        R.f1 = *(const float2*)(cm + 1 * HW + bs + Wn);
        R.f2 = *(const float2*)(cm + 2 * HW + bs + Wn);
        // boundary scalars: only the lane that uses them loads (1 line/instr)
        R.b0 = lnR ? cm[0 * HW + bs + Wn + 2] : 0.f;
        R.b3 = lnR ? cm[3 * HW + bs + 2]      : 0.f;
        R.b5 = lnR ? cm[5 * HW + bs - Wn + 2] : 0.f;
        R.b2 = lnL ? cm[2 * HW + bs + Wn - 1] : 0.f;
        R.b4 = lnL ? cm[4 * HW + bs - 1]      : 0.f;
        R.b7 = lnL ? cm[7 * HW + bs - Wn - 1] : 0.f;
        R.t  = *(const int2*)(tg + bs);
        R.u0 = *(const int2*)(ct + 0 * HW + bs);
        R.u1 = *(const int2*)(ct + 1 * HW + bs);
        R.u2 = *(const int2*)(ct + 2 * HW + bs);
        R.u3 = *(const int2*)(ct + 3 * HW + bs);
        R.u4 = *(const int2*)(ct + 4 * HW + bs);
        R.u5 = *(const int2*)(ct + 5 * HW + bs);
        R.u6 = *(const int2*)(ct + 6 * HW + bs);
        R.u7 = *(const int2*)(ct + 7 * HW + bs);
    };

    // ---- kick off first row's loads before prologue sigmas ----
    Row A, B;
    issue(hstart, A);

    // ---- carried window: sigma(ch0..2)@h, sigma(ch5..7)@h-1 ----
    float C0[2], C1[2], C2[2], P5[2], P6[2], P7[2];
    {
        const int pb = hstart * Wn + wq;
        sig2(*(const float2*)(cm + 0 * HW + pb), C0);
        sig2(*(const float2*)(cm + 1 * HW + pb), C1);
        sig2(*(const float2*)(cm + 2 * HW + pb), C2);
    }
    if (hstart > 0) {   // block-uniform
        const int pb = (hstart - 1) * Wn + wq;
        sig2(*(const float2*)(cm + 5 * HW + pb), P5);
        sig2(*(const float2*)(cm + 6 * HW + pb), P6);
        sig2(*(const float2*)(cm + 7 * HW + pb), P7);
    } else {
#pragma unroll
        for (int k = 0; k < 2; ++k) { P5[k] = 0.f; P6[k] = 0.f; P7[k] = 0.f; }
    }

    const bool edR = (wq + 2 == Wn);   // true only for wv3 lane63
    const bool edL = (wq == 0);        // true only for wv0 lane0

    // ---- per-row body: consumes Row R for image row h, updates windows ----
    auto body = [&](const Row& R, int h) {
        const bool hasDn = (h + 1 < Hn);
        const bool hasUp = (h > 0);

        // con bits
        unsigned lo = 0u;
        auto mix = [&](const int2& u, int c) {
            lo |= ((unsigned)u.x << c) | ((unsigned)u.y << (8 + c));
        };
        mix(R.u0, 0); mix(R.u1, 1); mix(R.u2, 2); mix(R.u3, 3);
        mix(R.u4, 4); mix(R.u5, 5); mix(R.u6, 6); mix(R.u7, 7);

        // fresh centers ch3-7: sigma + conmap d-product accumulation
        float dp[2] = {1.f, 1.f};   // prod of d over ch3..7
        float ys[2] = {0.f, 0.f};   // sum of y where bit==0
        float c3[2], c4[2], c5[2], c6[2], c7[2];
        auto fresh = [&](int c, const float2& v, float s[2]) {
            const float xs[2] = {v.x, v.y};
#pragma unroll
            for (int k = 0; k < 2; ++k) {
                const float y = xs[k] * L2E;
                const float e = fexp2(-y);
                const float d = 1.f + e;
                s[k] = frcp(d);
                dp[k] *= d;
                ys[k] += ((lo >> (8 * k + c)) & 1u) ? 0.f : y;
            }
        };
        fresh(3, R.a3, c3); fresh(4, R.a4, c4); fresh(5, R.a5, c5);
        fresh(6, R.a6, c6); fresh(7, R.a7, c7);

        // conmap: carried ch0-2 select-product + ch3-7 d-form
#pragma unroll
        for (int k = 0; k < 2; ++k) {
            const float q0 = ((lo >> (8 * k + 0)) & 1u) ? C0[k] : 1.f - C0[k];
            const float q1 = ((lo >> (8 * k + 1)) & 1u) ? C1[k] : 1.f - C1[k];
            const float q2 = ((lo >> (8 * k + 2)) & 1u) ? C2[k] : 1.f - C2[k];
            s_con += flog2(q0 * q1 * q2) - flog2(dp[k]) - ys[k];
        }

        // next-row sigmas
        float F0[2], F1[2], F2[2];
        sig2(R.f0, F0); sig2(R.f1, F1); sig2(R.f2, F2);

        // neighbor values: lane shuffle of already-computed sigmoids;
        // boundary lanes (0/63) fall back to scalar-load sigmoids
        const float r0 = __shfl_down(F0[0], 1);
        const float r3 = __shfl_down(c3[0], 1);
        const float r5 = __shfl_down(P5[0], 1);
        const float l2 = __shfl_up(F2[1], 1);
        const float l4 = __shfl_up(c4[1], 1);
        const float l7 = __shfl_up(P7[1], 1);
        const float s0b = frcp(1.f + fexp2(-R.b0 * L2E));
        const float s2b = frcp(1.f + fexp2(-R.b2 * L2E));
        const float s3b = frcp(1.f + fexp2(-R.b3 * L2E));
        const float s4b = frcp(1.f + fexp2(-R.b4 * L2E));
        const float s5b = frcp(1.f + fexp2(-R.b5 * L2E));
        const float s7b = frcp(1.f + fexp2(-R.b7 * L2E));

        // neighbor arrays n[c] (masked shifts)
        float n0[2], n1[2], n2[2], n3[2], n4[2], n5[2], n6[2], n7[2];
        n0[0] = F0[1]; n3[0] = c3[1]; n5[0] = P5[1];
        n2[1] = F2[0]; n4[1] = c4[0]; n7[1] = P7[0];
        n0[1] = edR ? 0.f : (lnR ? s0b : r0);
        n3[1] = edR ? 0.f : (lnR ? s3b : r3);
        n5[1] = edR ? 0.f : (lnR ? s5b : r5);
        n2[0] = edL ? 0.f : (lnL ? s2b : l2);
        n4[0] = edL ? 0.f : (lnL ? s4b : l4);
        n7[0] = edL ? 0.f : (lnL ? s7b : l7);
#pragma unroll
        for (int k = 0; k < 2; ++k) {
            n1[k] = hasDn ? F1[k] : 0.f;
            n6[k] = hasUp ? P6[k] : 0.f;
            if (!hasDn) { n0[k] = 0.f; n2[k] = 0.f; }
            if (!hasUp) { n5[k] = 0.f; n7[k] = 0.f; }
        }

        // votes + bimap product accumulation
        float vmax[2] = {0.f, 0.f}, vmin[2] = {2.f, 2.f};
        float pr[2]   = {1.f, 1.f};
        float zc[2]   = {0.f, 0.f};   // count of bit=1 zero-votes
        auto vote = [&](int i, const float p[2], const float n[2]) {
#pragma unroll
            for (int k = 0; k < 2; ++k) {
                const float v = p[k] * n[k];
                vmax[k] = fmaxf(vmax[k], v);
                vmin[k] = fminf(vmin[k], v);
                const bool bit = (lo >> (8 * k + i)) & 1u;
                const bool z   = bit && (v == 0.f);     // only from masked edges
                float sel = bit ? v : 1.f - v;
                sel = z ? 1.f : sel;
                zc[k] += z ? 1.f : 0.f;
                pr[k] *= sel;
            }
        };
        vote(0, C0, n7); vote(1, C1, n6); vote(2, C2, n5); vote(3, c3, n4);
#pragma unroll
        for (int k = 0; k < 2; ++k) { s_bi += flog2(pr[k]); pr[k] = 1.f; }
        vote(4, c4, n3); vote(5, c5, n2); vote(6, c6, n1); vote(7, c7, n0);
#pragma unroll
        for (int k = 0; k < 2; ++k) { s_bi += flog2(pr[k]) + CLMP * zc[k]; }

        // per-pixel tail
        const int tk[2] = {R.t.x, R.t.y};
#pragma unroll
        for (int k = 0; k < 2; ++k) {
            const float fm = vmax[k];
            s_bce += fmaxf(flog2(tk[k] ? fm : 1.f - fm), CLMP);
            const int sc = __popc((int)((lo >> (8 * k)) & 0xffu));
            s_dec += (sc > 0 && sc < 8) ? fmaxf(flog2(1.f - vmin[k]), CLMP) : 0.f;
            ci[k] += (float)tk[k];
            cj[k] += fm;
            cx[k] += tk[k] ? fm : 0.f;
        }

        // rotate window
#pragma unroll
        for (int k = 0; k < 2; ++k) {
            C0[k] = F0[k]; C1[k] = F1[k]; C2[k] = F2[k];
            P5[k] = c5[k]; P6[k] = c6[k]; P7[k] = c7[k];
        }
    };

    // ---- rolled ping-pong pipeline: 2 rows/iter, compile-time buffer roles,
    //      1-row prefetch depth, no Row copies, no dynamic indexing ----
#pragma unroll 1
    for (int r = 0; r < WALK; r += 2) {
        const int h = hstart + r;
        if (r + 1 < WALK) issue(h + 1, B);
        body(A, h);
        if (r + 2 < WALK) issue(h + 2, A);
        if (r + 1 < WALK) body(B, h + 1);
    }

    // ---- dice partials: thread-exclusive columns, direct store ----
    if constexpr (SLAB) {
        const size_t sb = ((size_t)work) << 9;
        float2 vi; vi.x = ci[0]; vi.y = ci[1];
        float2 vj; vj.x = cj[0]; vj.y = cj[1];
        float2 vx; vx.x = cx[0]; vx.y = cx[1];
        *(float2*)(col_i + sb + wq) = vi;
        *(float2*)(col_j + sb + wq) = vj;
        *(float2*)(col_x + sb + wq) = vx;
    } else {
#pragma unroll
        for (int k = 0; k < 2; ++k) {
            atomicAdd(&col_i[b * Wn + wq + k], ci[k]);
            atomicAdd(&col_j[b * Wn + wq + k], cj[k]);
            atomicAdd(&col_x[b * Wn + wq + k], cx[k]);
        }
    }

    // ---- scalar sums: wave shuffle reduction ----
#pragma unroll
    for (int off = 32; off > 0; off >>= 1) {
        s_con += __shfl_down(s_con, off);
        s_bi  += __shfl_down(s_bi,  off);
        s_bce += __shfl_down(s_bce, off);
        s_dec += __shfl_down(s_dec, off);
    }
    __shared__ float wred[4][4];
    if (lane == 0) {   // convert log2 -> ln units here (one mul per sum)
        wred[wv][0] = s_con * LN2; wred[wv][1] = s_bi * LN2;
        wred[wv][2] = s_bce * LN2; wred[wv][3] = s_dec * LN2;
    }
    __syncthreads();
    if (tid < 4) {
        bscal[(size_t)work * 4 + tid] =
            (double)(wred[0][tid] + wred[1][tid] + wred[2][tid] + wred[3][tid]);
    }
}

// Slab finisher: 256 blocks x 256 threads. Block bx owns 32 columns; each
// column's 64 gx-partials are summed by 8 threads (8 each) -> LDS -> lane.
__global__ __launch_bounds__(256) void bicon_finish_slab(
    const float* __restrict__ pI,
    const float* __restrict__ pJ,
    const float* __restrict__ pX,
    const double* __restrict__ bscal,
    float* __restrict__ out)
{
    const int tid = threadIdx.x;
    const int w32 = tid & 31;                 // which of the block's 32 columns
    const int p   = tid >> 5;                 // gx partition 0..7 (8 gx each)
    const int col = blockIdx.x * 32 + w32;    // 0..8191
    const int b   = col >> 9;
    const int w   = col & 511;

    float fi = 0.f, fj = 0.f, fx = 0.f;
    const size_t base = (((size_t)(b * GX + p * 8)) << 9) + w;
#pragma unroll
    for (int g = 0; g < 8; ++g) {
        const size_t idx = base + ((size_t)g << 9);
        fi += pI[idx]; fj += pJ[idx]; fx += pX[idx];
    }
    __shared__ float red[3][8][32];           // 3 KB
    red[0][p][w32] = fi; red[1][p][w32] = fj; red[2][p][w32] = fx;
    __syncthreads();

    double part = 0.0;
    if (tid < 32) {                           // dice term for 32 columns
        float si = 0.f, sj = 0.f, sx = 0.f;
#pragma unroll
        for (int q = 0; q < 8; ++q) {
            si += red[0][q][tid]; sj += red[1][q][tid]; sx += red[2][q][tid];
        }
        part = (1.0 - (2.0 * (double)sx + 0.001) /
                      ((double)si + (double)sj + 0.001)) / 8192.0;
    }
    if (tid >= 64 && tid < 68) {              // 4 bscal slots, on wave 1
        const int s = blockIdx.x * 4 + (tid - 64);
        const double c0 = bscal[s * 4 + 0], c1 = bscal[s * 4 + 1];
        const double c2 = bscal[s * 4 + 2], c3 = bscal[s * 4 + 3];
        part += -0.8 * c0 / 33554432.0 - 0.2 * c1 / 33554432.0
                - c2 / 4194304.0 - c3 / 4194304.0;
    }
#pragma unroll
    for (int off = 32; off > 0; off >>= 1) part += __shfl_down(part, off);
    __shared__ double red2[4];
    if ((tid & 63) == 0) red2[tid >> 6] = part;
    __syncthreads();
    if (tid == 0) atomicAdd(out, (float)(red2[0] + red2[1] + red2[2] + red2[3]));
}

// Fallback finisher (atomic path): cols already reduced, 32 blocks suffice.
__global__ __launch_bounds__(256) void bicon_finish(
    const float* __restrict__ col_i,
    const float* __restrict__ col_j,
    const float* __restrict__ col_x,
    const double* __restrict__ bscal,
    float* __restrict__ out)
{
    const int tid = threadIdx.x;
    const int col = blockIdx.x * 256 + tid;      // exactly NCOL threads total

    double part;
    {
        const float fi = col_i[col], fj = col_j[col], fx = col_x[col];
        part = (1.0 - (2.0 * (double)fx + 0.001) /
                      ((double)fi + (double)fj + 0.001)) / 8192.0;
    }
    if (tid < 32) {   // 32 bscal slots per block: 32 blocks * 32 = 1024 = NBLK
        const int s = blockIdx.x * 32 + tid;
        const double c0 = bscal[s * 4 + 0], c1 = bscal[s * 4 + 1];
        const double c2 = bscal[s * 4 + 2], c3 = bscal[s * 4 + 3];
        part += -0.8 * c0 / 33554432.0 - 0.2 * c1 / 33554432.0
                - c2 / 4194304.0 - c3 / 4194304.0;
    }
#pragma unroll
    for (int off = 32; off > 0; off >>= 1) part += __shfl_down(part, off);
    __shared__ double red[4];
    if ((tid & 63) == 0) red[tid >> 6] = part;
    __syncthreads();
    if (tid == 0) atomicAdd(out, (float)(red[0] + red[1] + red[2] + red[3]));
}

extern "C" void kernel_launch(void* const* d_in, const int* in_sizes, int n_in,
                              void* d_out, int out_size, void* d_ws, size_t ws_size,
                              hipStream_t stream) {
    const float* c_map      = (const float*)d_in[0];
    const int*   target     = (const int*)d_in[1];
    const int*   con_target = (const int*)d_in[2];
    float* out = (float*)d_out;

    char* ws = (char*)d_ws;
    const size_t slab_need = (size_t)3 * SLABN * sizeof(float)
                           + (size_t)NBLK * 4 * sizeof(double);   // ~6.33 MB

    dim3 grid(GX, Bn);       // 64 x 16 = 1024 blocks
    dim3 block(256);

    hipMemsetAsync(d_out, 0, sizeof(float), stream);  // finisher atomics here

    if (ws_size >= slab_need) {
        float*  pI    = (float*)ws;                   // 1024 x 512 partials
        float*  pJ    = pI + SLABN;
        float*  pX    = pJ + SLABN;
        double* bscal = (double*)(ws + (size_t)3 * SLABN * sizeof(float));
        // no col memset needed: slabs are fully written
        bicon_main<true><<<grid, block, 0, stream>>>(c_map, target, con_target,
                                                     pI, pJ, pX, bscal);
        bicon_finish_slab<<<FBLK2, 256, 0, stream>>>(pI, pJ, pX, bscal, out);
    } else {
        float*  col_i = (float*)ws;                               // 8192 floats
        float*  col_j = col_i + NCOL;
        float*  col_x = col_j + NCOL;
        double* bscal = (double*)(ws + 3 * NCOL * sizeof(float)); // 1024*4 doubles
        hipMemsetAsync(d_ws, 0, 3 * NCOL * sizeof(float), stream);
        bicon_main<false><<<grid, block, 0, stream>>>(c_map, target, con_target,
                                                      col_i, col_j, col_x, bscal);
        bicon_finish<<<FBLK, 256, 0, stream>>>(col_i, col_j, col_x, bscal, out);
    }
}

// Round 6
// 289.846 us; speedup vs baseline: 1.1512x; 1.0573x over previous
//
#include <hip/hip_runtime.h>

namespace {
constexpr int Bn = 16, Hn = 512, Wn = 512;
constexpr int HW  = Hn * Wn;        // 262144
constexpr int CHW = 8 * HW;         // 2097152
constexpr int NCOL = Bn * Wn;       // 8192 dice columns
constexpr int WALK = 4;             // rows walked per thread
constexpr int GX   = Hn / WALK;     // 128
constexpr int NBLK = GX * Bn;       // 2048 blocks
constexpr int SLABN = NBLK * 512;   // 1,048,576 floats per partial table
constexpr int FBLK  = 32;           // fallback finisher blocks
constexpr int FBLK2 = 256;          // slab finisher blocks (8 bscal slots each)

constexpr float L2E  = 1.4426950408889634f;   // log2(e)
constexpr float LN2  = 0.6931471805599453f;
constexpr float CLMP = -144.26950408889634f;  // -100 / ln2 (clamp in log2 units)

__device__ __forceinline__ float frcp(float x) { return __builtin_amdgcn_rcpf(x); }
#if __has_builtin(__builtin_amdgcn_exp2f)
__device__ __forceinline__ float fexp2(float x) { return __builtin_amdgcn_exp2f(x); }
#else
__device__ __forceinline__ float fexp2(float x) { return exp2f(x); }
#endif
#if __has_builtin(__builtin_amdgcn_logf)
__device__ __forceinline__ float flog2(float x) { return __builtin_amdgcn_logf(x); }
#else
__device__ __forceinline__ float flog2(float x) { return log2f(x); }
#endif

// non-temporal (streaming, no-L1-allocate) loads
typedef float vf2 __attribute__((ext_vector_type(2)));
typedef int   vi2 __attribute__((ext_vector_type(2)));
__device__ __forceinline__ vf2 ntl2f(const float* p) {
    return __builtin_nontemporal_load((const vf2*)p);
}
__device__ __forceinline__ vi2 ntl2i(const int* p) {
    return __builtin_nontemporal_load((const vi2*)p);
}
__device__ __forceinline__ float ntlf(const float* p) {
    return __builtin_nontemporal_load(p);
}
} // namespace

// n[c](h,w) = sigmoid(c_map[c][h+DY[c]][w+DX[c]]), zero outside image.
// vote[i] = p[i] * n[7-i].  DX = {1,0,-1,1,-1,1,0,-1}, DY = {1,1,1,0,0,-1,-1,-1}.
// BCE sums in log2 units via log-of-product fusion; one x ln2 at bscal write.
//
// R6: L1-bypass probe. Null matrix so far: occupancy (11-55%), granularity
// (8/16B), ILP (0/1-row prefetch), HBM bytes (-17%), L1 bytes (-7%), XCD
// swizzle -- all ~null at ~112-122us, while R1 proved the memory system
// sustains 3.8 TB/s with the SAME demand streams + scratch. Theory: the 26
// per-wave streams sit at exact 1MiB stride -> identical L1 set-index bits
// -> all streams of all co-resident blocks alias into the same 32KiB-L1
// sets -> permanent fill/evict thrash caps delivery. Data is single-use at
// L1 timescales, so: __builtin_nontemporal_load (nt, no L1 allocate) on
// every main-loop load. Structure = R3 exactly (best known: 112us).
// Also: con/target loads issued FIRST (first consumers -> partial-vmcnt win).
// Tripwires: VGPR ~104, WRITE_SIZE ~12.4MB; if dur null +-4us -> declare
// pattern roofline (translation/miss-queue serialization, not fixable here).

struct Row {
    float2 a3, a4, a5, a6, a7;   // row h, ch3-7
    float2 f0, f1, f2;           // row h+1, ch0-2
    float  b0, b2, b3, b4, b5, b7;  // boundary scalars for row h
    int2   t;                    // target row h
    int2   u0, u1, u2, u3, u4, u5, u6, u7;  // con_target row h
};

template <bool SLAB>
__global__ __launch_bounds__(256) void bicon_main(
    const float* __restrict__ c_map,
    const int*   __restrict__ target,
    const int*   __restrict__ con_target,
    float* __restrict__ col_i, float* __restrict__ col_j, float* __restrict__ col_x,
    double* __restrict__ bscal)
{
    const int tid  = threadIdx.x;        // 0..255
    const int lane = tid & 63;
    const int wv   = tid >> 6;           // 0..3 = column quarter

    // Bijective XCD-chunk swizzle: each XCD owns 256 consecutive work ids.
    const int hwid = blockIdx.y * GX + blockIdx.x;
    const int work = (hwid & 7) * (NBLK / 8) + (hwid >> 3);
    const int gx   = work & (GX - 1);
    const int b    = work >> 7;          // work / GX

    const int hstart = gx * WALK;
    const int wq   = wv * 128 + lane * 2;   // first of this lane's 2 columns

    const float* cm = c_map      + (size_t)b * CHW;
    const int*   ct = con_target + (size_t)b * CHW;
    const int*   tg = target     + (size_t)b * HW;

    float s_con = 0.f, s_bi = 0.f, s_bce = 0.f, s_dec = 0.f;   // log2 units
    float ci[2] = {0, 0}, cj[2] = {0, 0}, cx[2] = {0, 0};

    auto sig2v = [&](const vf2& v, float s[2]) {
        s[0] = frcp(1.f + fexp2(-v.x * L2E));
        s[1] = frcp(1.f + fexp2(-v.y * L2E));
    };
    auto sig2 = [&](const float2& v, float s[2]) {
        s[0] = frcp(1.f + fexp2(-v.x * L2E));
        s[1] = frcp(1.f + fexp2(-v.y * L2E));
    };

    auto issue = [&](int hh, Row& R) {
        const int bs = hh * Wn + wq;
        // first consumers first: con bits + target
        vi2 v;
        v = ntl2i(ct + 0 * HW + bs); R.u0.x = v.x; R.u0.y = v.y;
        v = ntl2i(ct + 1 * HW + bs); R.u1.x = v.x; R.u1.y = v.y;
        v = ntl2i(ct + 2 * HW + bs); R.u2.x = v.x; R.u2.y = v.y;
        v = ntl2i(ct + 3 * HW + bs); R.u3.x = v.x; R.u3.y = v.y;
        v = ntl2i(ct + 4 * HW + bs); R.u4.x = v.x; R.u4.y = v.y;
        v = ntl2i(ct + 5 * HW + bs); R.u5.x = v.x; R.u5.y = v.y;
        v = ntl2i(ct + 6 * HW + bs); R.u6.x = v.x; R.u6.y = v.y;
        v = ntl2i(ct + 7 * HW + bs); R.u7.x = v.x; R.u7.y = v.y;
        v = ntl2i(tg + bs);          R.t.x  = v.x; R.t.y  = v.y;
        vf2 f;
        f = ntl2f(cm + 3 * HW + bs); R.a3.x = f.x; R.a3.y = f.y;
        f = ntl2f(cm + 4 * HW + bs); R.a4.x = f.x; R.a4.y = f.y;
        f = ntl2f(cm + 5 * HW + bs); R.a5.x = f.x; R.a5.y = f.y;
        f = ntl2f(cm + 6 * HW + bs); R.a6.x = f.x; R.a6.y = f.y;
        f = ntl2f(cm + 7 * HW + bs); R.a7.x = f.x; R.a7.y = f.y;
        f = ntl2f(cm + 0 * HW + bs + Wn); R.f0.x = f.x; R.f0.y = f.y;
        f = ntl2f(cm + 1 * HW + bs + Wn); R.f1.x = f.x; R.f1.y = f.y;
        f = ntl2f(cm + 2 * HW + bs + Wn); R.f2.x = f.x; R.f2.y = f.y;
        R.b0 = ntlf(cm + 0 * HW + bs + Wn + 2);
        R.b2 = ntlf(cm + 2 * HW + bs + Wn - 1);
        R.b3 = ntlf(cm + 3 * HW + bs + 2);
        R.b4 = ntlf(cm + 4 * HW + bs - 1);
        R.b5 = ntlf(cm + 5 * HW + bs - Wn + 2);
        R.b7 = ntlf(cm + 7 * HW + bs - Wn - 1);
    };

    // ---- kick off row hstart loads FIRST (fly under prologue sigmas) ----
    Row cu, nx;
    issue(hstart, cu);

    // ---- carried window: sigma(ch0..2)@h, sigma(ch5..7)@h-1 ----
    float C0[2], C1[2], C2[2], P5[2], P6[2], P7[2];
    {
        const int pb = hstart * Wn + wq;
        sig2v(ntl2f(cm + 0 * HW + pb), C0);
        sig2v(ntl2f(cm + 1 * HW + pb), C1);
        sig2v(ntl2f(cm + 2 * HW + pb), C2);
    }
    if (hstart > 0) {   // block-uniform
        const int pb = (hstart - 1) * Wn + wq;
        sig2v(ntl2f(cm + 5 * HW + pb), P5);
        sig2v(ntl2f(cm + 6 * HW + pb), P6);
        sig2v(ntl2f(cm + 7 * HW + pb), P7);
    } else {
#pragma unroll
        for (int k = 0; k < 2; ++k) { P5[k] = 0.f; P6[k] = 0.f; P7[k] = 0.f; }
    }

    const bool edR = (wq + 2 == Wn);
    const bool edL = (wq == 0);

#pragma unroll
    for (int r = 0; r < WALK; ++r) {
        const int  h     = hstart + r;
        const bool hasDn = (h + 1 < Hn);
        const bool hasUp = (h > 0);

        // ---- prefetch next row before touching cu (compile-time guard) ----
        if (r + 1 < WALK) issue(h + 1, nx);

        // ---- con bits ----
        unsigned lo = 0u;
        auto mix = [&](const int2& u, int c) {
            lo |= ((unsigned)u.x << c) | ((unsigned)u.y << (8 + c));
        };
        mix(cu.u0, 0); mix(cu.u1, 1); mix(cu.u2, 2); mix(cu.u3, 3);
        mix(cu.u4, 4); mix(cu.u5, 5); mix(cu.u6, 6); mix(cu.u7, 7);

        // ---- fresh centers ch3-7: sigma + conmap d-product accumulation ----
        float dp[2] = {1.f, 1.f};   // prod of d over ch3..7
        float ys[2] = {0.f, 0.f};   // sum of y where bit==0
        float c3[2], c4[2], c5[2], c6[2], c7[2];
        auto fresh = [&](int c, const float2& v, float s[2]) {
            const float xs[2] = {v.x, v.y};
#pragma unroll
            for (int k = 0; k < 2; ++k) {
                const float y = xs[k] * L2E;
                const float e = fexp2(-y);
                const float d = 1.f + e;
                s[k] = frcp(d);
                dp[k] *= d;
                ys[k] += ((lo >> (8 * k + c)) & 1u) ? 0.f : y;
            }
        };
        fresh(3, cu.a3, c3); fresh(4, cu.a4, c4); fresh(5, cu.a5, c5);
        fresh(6, cu.a6, c6); fresh(7, cu.a7, c7);

        // ---- conmap: carried ch0-2 select-product + ch3-7 d-form ----
#pragma unroll
        for (int k = 0; k < 2; ++k) {
            const float q0 = ((lo >> (8 * k + 0)) & 1u) ? C0[k] : 1.f - C0[k];
            const float q1 = ((lo >> (8 * k + 1)) & 1u) ? C1[k] : 1.f - C1[k];
            const float q2 = ((lo >> (8 * k + 2)) & 1u) ? C2[k] : 1.f - C2[k];
            s_con += flog2(q0 * q1 * q2) - flog2(dp[k]) - ys[k];
        }

        // ---- next-row sigmas + boundary sigmas ----
        float F0[2], F1[2], F2[2];
        sig2(cu.f0, F0); sig2(cu.f1, F1); sig2(cu.f2, F2);
        const float s0b = frcp(1.f + fexp2(-cu.b0 * L2E));
        const float s2b = frcp(1.f + fexp2(-cu.b2 * L2E));
        const float s3b = frcp(1.f + fexp2(-cu.b3 * L2E));
        const float s4b = frcp(1.f + fexp2(-cu.b4 * L2E));
        const float s5b = frcp(1.f + fexp2(-cu.b5 * L2E));
        const float s7b = frcp(1.f + fexp2(-cu.b7 * L2E));

        // ---- neighbor arrays n[c] (masked shifts) ----
        float n0[2], n1[2], n2[2], n3[2], n4[2], n5[2], n6[2], n7[2];
        n0[0] = F0[1]; n3[0] = c3[1]; n5[0] = P5[1];
        n2[1] = F2[0]; n4[1] = c4[0]; n7[1] = P7[0];
        n0[1] = edR ? 0.f : s0b;  n3[1] = edR ? 0.f : s3b;  n5[1] = edR ? 0.f : s5b;
        n2[0] = edL ? 0.f : s2b;  n4[0] = edL ? 0.f : s4b;  n7[0] = edL ? 0.f : s7b;
#pragma unroll
        for (int k = 0; k < 2; ++k) {
            n1[k] = hasDn ? F1[k] : 0.f;
            n6[k] = hasUp ? P6[k] : 0.f;
            if (!hasDn) { n0[k] = 0.f; n2[k] = 0.f; }
            if (!hasUp) { n5[k] = 0.f; n7[k] = 0.f; }
        }

        // ---- votes + bimap product accumulation ----
        float vmax[2] = {0.f, 0.f}, vmin[2] = {2.f, 2.f};
        float pr[2]   = {1.f, 1.f};
        float zc[2]   = {0.f, 0.f};   // count of bit=1 zero-votes
        auto vote = [&](int i, const float p[2], const float n[2]) {
#pragma unroll
            for (int k = 0; k < 2; ++k) {
                const float v = p[k] * n[k];
                vmax[k] = fmaxf(vmax[k], v);
                vmin[k] = fminf(vmin[k], v);
                const bool bit = (lo >> (8 * k + i)) & 1u;
                const bool z   = bit && (v == 0.f);     // only from masked edges
                float sel = bit ? v : 1.f - v;
                sel = z ? 1.f : sel;
                zc[k] += z ? 1.f : 0.f;
                pr[k] *= sel;
            }
        };
        vote(0, C0, n7); vote(1, C1, n6); vote(2, C2, n5); vote(3, c3, n4);
#pragma unroll
        for (int k = 0; k < 2; ++k) { s_bi += flog2(pr[k]); pr[k] = 1.f; }
        vote(4, c4, n3); vote(5, c5, n2); vote(6, c6, n1); vote(7, c7, n0);
#pragma unroll
        for (int k = 0; k < 2; ++k) { s_bi += flog2(pr[k]) + CLMP * zc[k]; }

        // ---- per-pixel tail ----
        const int tk[2] = {cu.t.x, cu.t.y};
#pragma unroll
        for (int k = 0; k < 2; ++k) {
            const float fm = vmax[k];
            s_bce += fmaxf(flog2(tk[k] ? fm : 1.f - fm), CLMP);
            const int sc = __popc((int)((lo >> (8 * k)) & 0xffu));
            s_dec += (sc > 0 && sc < 8) ? fmaxf(flog2(1.f - vmin[k]), CLMP) : 0.f;
            ci[k] += (float)tk[k];
            cj[k] += fm;
            cx[k] += tk[k] ? fm : 0.f;
        }

        // ---- rotate window + pipeline ----
#pragma unroll
        for (int k = 0; k < 2; ++k) {
            C0[k] = F0[k]; C1[k] = F1[k]; C2[k] = F2[k];
            P5[k] = c5[k]; P6[k] = c6[k]; P7[k] = c7[k];
        }
        if (r + 1 < WALK) cu = nx;   // waits for nx here == start of next iter
    }

    // ---- dice partials: thread-exclusive columns, direct store ----
    if constexpr (SLAB) {
        const size_t sb = ((size_t)work) << 9;
        float2 vi; vi.x = ci[0]; vi.y = ci[1];
        float2 vj; vj.x = cj[0]; vj.y = cj[1];
        float2 vx; vx.x = cx[0]; vx.y = cx[1];
        *(float2*)(col_i + sb + wq) = vi;
        *(float2*)(col_j + sb + wq) = vj;
        *(float2*)(col_x + sb + wq) = vx;
    } else {
#pragma unroll
        for (int k = 0; k < 2; ++k) {
            atomicAdd(&col_i[b * Wn + wq + k], ci[k]);
            atomicAdd(&col_j[b * Wn + wq + k], cj[k]);
            atomicAdd(&col_x[b * Wn + wq + k], cx[k]);
        }
    }

    // ---- scalar sums: wave shuffle reduction ----
#pragma unroll
    for (int off = 32; off > 0; off >>= 1) {
        s_con += __shfl_down(s_con, off);
        s_bi  += __shfl_down(s_bi,  off);
        s_bce += __shfl_down(s_bce, off);
        s_dec += __shfl_down(s_dec, off);
    }
    __shared__ float wred[4][4];
    if (lane == 0) {   // convert log2 -> ln units here (one mul per sum)
        wred[wv][0] = s_con * LN2; wred[wv][1] = s_bi * LN2;
        wred[wv][2] = s_bce * LN2; wred[wv][3] = s_dec * LN2;
    }
    __syncthreads();
    if (tid < 4) {
        bscal[(size_t)work * 4 + tid] =
            (double)(wred[0][tid] + wred[1][tid] + wred[2][tid] + wred[3][tid]);
    }
}

// Slab finisher: 256 blocks x 256 threads. Block bx owns 32 columns; each
// column's 128 gx-partials are summed by 8 threads (16 each) -> LDS -> lane.
__global__ __launch_bounds__(256) void bicon_finish_slab(
    const float* __restrict__ pI,
    const float* __restrict__ pJ,
    const float* __restrict__ pX,
    const double* __restrict__ bscal,
    float* __restrict__ out)
{
    const int tid = threadIdx.x;
    const int w32 = tid & 31;                 // which of the block's 32 columns
    const int p   = tid >> 5;                 // gx partition 0..7 (16 gx each)
    const int col = blockIdx.x * 32 + w32;    // 0..8191
    const int b   = col >> 9;
    const int w   = col & 511;

    float fi = 0.f, fj = 0.f, fx = 0.f;
    const size_t base = (((size_t)(b * GX + p * 16)) << 9) + w;
#pragma unroll
    for (int g = 0; g < 16; ++g) {
        const size_t idx = base + ((size_t)g << 9);
        fi += pI[idx]; fj += pJ[idx]; fx += pX[idx];
    }
    __shared__ float red[3][8][32];           // 3 KB
    red[0][p][w32] = fi; red[1][p][w32] = fj; red[2][p][w32] = fx;
    __syncthreads();

    double part = 0.0;
    if (tid < 32) {                           // dice term for 32 columns
        float si = 0.f, sj = 0.f, sx = 0.f;
#pragma unroll
        for (int q = 0; q < 8; ++q) {
            si += red[0][q][tid]; sj += red[1][q][tid]; sx += red[2][q][tid];
        }
        part = (1.0 - (2.0 * (double)sx + 0.001) /
                      ((double)si + (double)sj + 0.001)) / 8192.0;
    }
    if (tid >= 64 && tid < 72) {              // 8 bscal slots, on wave 1
        const int s = blockIdx.x * 8 + (tid - 64);
        const double c0 = bscal[s * 4 + 0], c1 = bscal[s * 4 + 1];
        const double c2 = bscal[s * 4 + 2], c3 = bscal[s * 4 + 3];
        part += -0.8 * c0 / 33554432.0 - 0.2 * c1 / 33554432.0
                - c2 / 4194304.0 - c3 / 4194304.0;
    }
#pragma unroll
    for (int off = 32; off > 0; off >>= 1) part += __shfl_down(part, off);
    __shared__ double red2[4];
    if ((tid & 63) == 0) red2[tid >> 6] = part;
    __syncthreads();
    if (tid == 0) atomicAdd(out, (float)(red2[0] + red2[1] + red2[2] + red2[3]));
}

// Fallback finisher (atomic path): cols already reduced, 32 blocks suffice.
__global__ __launch_bounds__(256) void bicon_finish(
    const float* __restrict__ col_i,
    const float* __restrict__ col_j,
    const float* __restrict__ col_x,
    const double* __restrict__ bscal,
    float* __restrict__ out)
{
    const int tid = threadIdx.x;
    const int col = blockIdx.x * 256 + tid;      // exactly NCOL threads total

    double part;
    {
        const float fi = col_i[col], fj = col_j[col], fx = col_x[col];
        part = (1.0 - (2.0 * (double)fx + 0.001) /
                      ((double)fi + (double)fj + 0.001)) / 8192.0;
    }
    if (tid < 64) {   // 64 bscal slots per block: 32 blocks * 64 = 2048 = NBLK
        const int s = blockIdx.x * 64 + tid;
        const double c0 = bscal[s * 4 + 0], c1 = bscal[s * 4 + 1];
        const double c2 = bscal[s * 4 + 2], c3 = bscal[s * 4 + 3];
        part += -0.8 * c0 / 33554432.0 - 0.2 * c1 / 33554432.0
                - c2 / 4194304.0 - c3 / 4194304.0;
    }
#pragma unroll
    for (int off = 32; off > 0; off >>= 1) part += __shfl_down(part, off);
    __shared__ double red[4];
    if ((tid & 63) == 0) red[tid >> 6] = part;
    __syncthreads();
    if (tid == 0) atomicAdd(out, (float)(red[0] + red[1] + red[2] + red[3]));
}

extern "C" void kernel_launch(void* const* d_in, const int* in_sizes, int n_in,
                              void* d_out, int out_size, void* d_ws, size_t ws_size,
                              hipStream_t stream) {
    const float* c_map      = (const float*)d_in[0];
    const int*   target     = (const int*)d_in[1];
    const int*   con_target = (const int*)d_in[2];
    float* out = (float*)d_out;

    char* ws = (char*)d_ws;
    const size_t slab_need = (size_t)3 * SLABN * sizeof(float)
                           + (size_t)NBLK * 4 * sizeof(double);   // ~12.65 MB

    dim3 grid(GX, Bn);       // 128 x 16 = 2048 blocks
    dim3 block(256);

    hipMemsetAsync(d_out, 0, sizeof(float), stream);  // finisher atomics here

    if (ws_size >= slab_need) {
        float*  pI    = (float*)ws;                   // 2048 x 512 partials
        float*  pJ    = pI + SLABN;
        float*  pX    = pJ + SLABN;
        double* bscal = (double*)(ws + (size_t)3 * SLABN * sizeof(float));
        // no col memset needed: slabs are fully written
        bicon_main<true><<<grid, block, 0, stream>>>(c_map, target, con_target,
                                                     pI, pJ, pX, bscal);
        bicon_finish_slab<<<FBLK2, 256, 0, stream>>>(pI, pJ, pX, bscal, out);
    } else {
        float*  col_i = (float*)ws;                               // 8192 floats
        float*  col_j = col_i + NCOL;
        float*  col_x = col_j + NCOL;
        double* bscal = (double*)(ws + 3 * NCOL * sizeof(float)); // 2048*4 doubles
        hipMemsetAsync(d_ws, 0, 3 * NCOL * sizeof(float), stream);
        bicon_main<false><<<grid, block, 0, stream>>>(c_map, target, con_target,
                                                      col_i, col_j, col_x, bscal);
        bicon_finish<<<FBLK, 256, 0, stream>>>(col_i, col_j, col_x, bscal, out);
    }
}

// Round 7
// 289.644 us; speedup vs baseline: 1.1520x; 1.0007x over previous
//
#include <hip/hip_runtime.h>

namespace {
constexpr int Bn = 16, Hn = 512, Wn = 512;
constexpr int HW  = Hn * Wn;        // 262144
constexpr int CHW = 8 * HW;         // 2097152
constexpr int NCOL = Bn * Wn;       // 8192 dice columns
constexpr int WALK = 4;             // rows walked per thread
constexpr int GX   = Hn / WALK;     // 128
constexpr int NBLK = GX * Bn;       // 2048 blocks
constexpr int SLABN = NBLK * 512;   // 1,048,576 floats per partial table
constexpr int FBLK  = 32;           // fallback finisher blocks
constexpr int FBLK2 = 256;          // slab finisher blocks (8 bscal slots each)

constexpr float L2E  = 1.4426950408889634f;   // log2(e)
constexpr float LN2  = 0.6931471805599453f;
constexpr float CLMP = -144.26950408889634f;  // -100 / ln2 (clamp in log2 units)

__device__ __forceinline__ float frcp(float x) { return __builtin_amdgcn_rcpf(x); }
#if __has_builtin(__builtin_amdgcn_exp2f)
__device__ __forceinline__ float fexp2(float x) { return __builtin_amdgcn_exp2f(x); }
#else
__device__ __forceinline__ float fexp2(float x) { return exp2f(x); }
#endif
#if __has_builtin(__builtin_amdgcn_logf)
__device__ __forceinline__ float flog2(float x) { return __builtin_amdgcn_logf(x); }
#else
__device__ __forceinline__ float flog2(float x) { return log2f(x); }
#endif

// non-temporal (streaming, no-L1-allocate) loads — R6's proven lever
typedef float vf2 __attribute__((ext_vector_type(2)));
typedef int   vi2 __attribute__((ext_vector_type(2)));
__device__ __forceinline__ vf2 ntl2f(const float* p) {
    return __builtin_nontemporal_load((const vf2*)p);
}
__device__ __forceinline__ vi2 ntl2i(const int* p) {
    return __builtin_nontemporal_load((const vi2*)p);
}
__device__ __forceinline__ float ntlf(const float* p) {
    return __builtin_nontemporal_load(p);
}
} // namespace

// n[c](h,w) = sigmoid(c_map[c][h+DY[c]][w+DX[c]]), zero outside image.
// vote[i] = p[i] * n[7-i].  DX = {1,0,-1,1,-1,1,0,-1}, DY = {1,1,1,0,0,-1,-1,-1}.
// BCE sums in log2 units via log-of-product fusion; one x ln2 at bscal write.
//
// R7: occupancy re-probe in the STREAMING regime. R6 proved the R0-R5 wall
// was L1 set-alias thrash (26 streams at exact 1MiB stride); NT loads broke
// it (main 112 -> <77us). All earlier "occupancy-null" results were measured
// inside the thrash regime and are void. This round: R2's register-lean
// rolled structure (VGPR ~36-45 -> ~55% occ, ~3x the resident waves) + NT
// everywhere + XCD swizzle + slab stores. In a latency/outstanding-request
// regime, delivered BW should scale with waves: predict main ~55-62us.
// If it regresses instead, R6 (prefetch-ILP) is the keeper -> revert.

template <bool SLAB>
__global__ __launch_bounds__(256) void bicon_main(
    const float* __restrict__ c_map,
    const int*   __restrict__ target,
    const int*   __restrict__ con_target,
    float* __restrict__ col_i, float* __restrict__ col_j, float* __restrict__ col_x,
    double* __restrict__ bscal)
{
    const int tid  = threadIdx.x;        // 0..255
    const int lane = tid & 63;
    const int wv   = tid >> 6;           // 0..3 = column quarter

    // Bijective XCD-chunk swizzle: each XCD owns 256 consecutive work ids.
    const int hwid = blockIdx.y * GX + blockIdx.x;
    const int work = (hwid & 7) * (NBLK / 8) + (hwid >> 3);
    const int gx   = work & (GX - 1);
    const int b    = work >> 7;          // work / GX

    const int hstart = gx * WALK;
    const int wq   = wv * 128 + lane * 2;   // first of this lane's 2 columns

    const float* cm = c_map      + (size_t)b * CHW;
    const int*   ct = con_target + (size_t)b * CHW;
    const int*   tg = target     + (size_t)b * HW;

    float s_con = 0.f, s_bi = 0.f, s_bce = 0.f, s_dec = 0.f;   // log2 units
    float ci[2] = {0, 0}, cj[2] = {0, 0}, cx[2] = {0, 0};

    auto sig2v = [&](const vf2& v, float s[2]) {
        s[0] = frcp(1.f + fexp2(-v.x * L2E));
        s[1] = frcp(1.f + fexp2(-v.y * L2E));
    };

    // ---- carried window: sigma(ch0..2)@h, sigma(ch5..7)@h-1 ----
    float C0[2], C1[2], C2[2], P5[2], P6[2], P7[2];
    {
        const int pb = hstart * Wn + wq;
        sig2v(ntl2f(cm + 0 * HW + pb), C0);
        sig2v(ntl2f(cm + 1 * HW + pb), C1);
        sig2v(ntl2f(cm + 2 * HW + pb), C2);
    }
    if (hstart > 0) {   // block-uniform
        const int pb = (hstart - 1) * Wn + wq;
        sig2v(ntl2f(cm + 5 * HW + pb), P5);
        sig2v(ntl2f(cm + 6 * HW + pb), P6);
        sig2v(ntl2f(cm + 7 * HW + pb), P7);
    } else {
#pragma unroll
        for (int k = 0; k < 2; ++k) { P5[k] = 0.f; P6[k] = 0.f; P7[k] = 0.f; }
    }

    const bool edR = (wq + 2 == Wn);
    const bool edL = (wq == 0);

    int h = hstart;
#pragma unroll 1
    for (int r = 0; r < WALK; ++r, ++h) {
        const int  base  = h * Wn + wq;
        const bool hasDn = (h + 1 < Hn);
        const bool hasUp = (h > 0);

        // ---- all loads issued up front (compiler interleaves waits) ----
        const vf2 xa3 = ntl2f(cm + 3 * HW + base);
        const vf2 xa4 = ntl2f(cm + 4 * HW + base);
        const vf2 xa5 = ntl2f(cm + 5 * HW + base);
        const vf2 xa6 = ntl2f(cm + 6 * HW + base);
        const vf2 xa7 = ntl2f(cm + 7 * HW + base);
        const vf2 xf0 = ntl2f(cm + 0 * HW + base + Wn);
        const vf2 xf1 = ntl2f(cm + 1 * HW + base + Wn);
        const vf2 xf2 = ntl2f(cm + 2 * HW + base + Wn);
        const float bx0 = ntlf(cm + 0 * HW + base + Wn + 2);
        const float bx2 = ntlf(cm + 2 * HW + base + Wn - 1);
        const float bx3 = ntlf(cm + 3 * HW + base + 2);
        const float bx4 = ntlf(cm + 4 * HW + base - 1);
        const float bx5 = ntlf(cm + 5 * HW + base - Wn + 2);
        const float bx7 = ntlf(cm + 7 * HW + base - Wn - 1);
        const vi2 t2 = ntl2i(tg + base);

        unsigned lo = 0u;
#pragma unroll
        for (int c = 0; c < 8; ++c) {
            const vi2 u = ntl2i(ct + c * HW + base);
            lo |= ((unsigned)u.x << c) | ((unsigned)u.y << (8 + c));
        }

        // ---- fresh centers ch3-7: sigma + conmap d-product accumulation ----
        float dp[2] = {1.f, 1.f};   // prod of d over ch3..7
        float ys[2] = {0.f, 0.f};   // sum of y where bit==0
        float c3[2], c4[2], c5[2], c6[2], c7[2];
        auto fresh = [&](int c, const vf2& v, float s[2]) {
            const float xs[2] = {v.x, v.y};
#pragma unroll
            for (int k = 0; k < 2; ++k) {
                const float y = xs[k] * L2E;
                const float e = fexp2(-y);
                const float d = 1.f + e;
                s[k] = frcp(d);
                dp[k] *= d;
                ys[k] += ((lo >> (8 * k + c)) & 1u) ? 0.f : y;
            }
        };
        fresh(3, xa3, c3); fresh(4, xa4, c4); fresh(5, xa5, c5);
        fresh(6, xa6, c6); fresh(7, xa7, c7);

        // ---- conmap: carried ch0-2 select-product + ch3-7 d-form ----
#pragma unroll
        for (int k = 0; k < 2; ++k) {
            const float q0 = ((lo >> (8 * k + 0)) & 1u) ? C0[k] : 1.f - C0[k];
            const float q1 = ((lo >> (8 * k + 1)) & 1u) ? C1[k] : 1.f - C1[k];
            const float q2 = ((lo >> (8 * k + 2)) & 1u) ? C2[k] : 1.f - C2[k];
            s_con += flog2(q0 * q1 * q2) - flog2(dp[k]) - ys[k];
        }

        // ---- next-row sigmas + boundary sigmas ----
        float F0[2], F1[2], F2[2];
        sig2v(xf0, F0); sig2v(xf1, F1); sig2v(xf2, F2);
        const float s0b = frcp(1.f + fexp2(-bx0 * L2E));
        const float s2b = frcp(1.f + fexp2(-bx2 * L2E));
        const float s3b = frcp(1.f + fexp2(-bx3 * L2E));
        const float s4b = frcp(1.f + fexp2(-bx4 * L2E));
        const float s5b = frcp(1.f + fexp2(-bx5 * L2E));
        const float s7b = frcp(1.f + fexp2(-bx7 * L2E));

        // ---- neighbor arrays n[c] (masked shifts) ----
        float n0[2], n1[2], n2[2], n3[2], n4[2], n5[2], n6[2], n7[2];
        n0[0] = F0[1]; n3[0] = c3[1]; n5[0] = P5[1];
        n2[1] = F2[0]; n4[1] = c4[0]; n7[1] = P7[0];
        n0[1] = edR ? 0.f : s0b;  n3[1] = edR ? 0.f : s3b;  n5[1] = edR ? 0.f : s5b;
        n2[0] = edL ? 0.f : s2b;  n4[0] = edL ? 0.f : s4b;  n7[0] = edL ? 0.f : s7b;
#pragma unroll
        for (int k = 0; k < 2; ++k) {
            n1[k] = hasDn ? F1[k] : 0.f;
            n6[k] = hasUp ? P6[k] : 0.f;
            if (!hasDn) { n0[k] = 0.f; n2[k] = 0.f; }
            if (!hasUp) { n5[k] = 0.f; n7[k] = 0.f; }
        }

        // ---- votes + bimap product accumulation ----
        float vmax[2] = {0.f, 0.f}, vmin[2] = {2.f, 2.f};
        float pr[2]   = {1.f, 1.f};
        float zc[2]   = {0.f, 0.f};   // count of bit=1 zero-votes
        auto vote = [&](int i, const float p[2], const float n[2]) {
#pragma unroll
            for (int k = 0; k < 2; ++k) {
                const float v = p[k] * n[k];
                vmax[k] = fmaxf(vmax[k], v);
                vmin[k] = fminf(vmin[k], v);
                const bool bit = (lo >> (8 * k + i)) & 1u;
                const bool z   = bit && (v == 0.f);     // only from masked edges
                float sel = bit ? v : 1.f - v;
                sel = z ? 1.f : sel;
                zc[k] += z ? 1.f : 0.f;
                pr[k] *= sel;
            }
        };
        vote(0, C0, n7); vote(1, C1, n6); vote(2, C2, n5); vote(3, c3, n4);
#pragma unroll
        for (int k = 0; k < 2; ++k) { s_bi += flog2(pr[k]); pr[k] = 1.f; }
        vote(4, c4, n3); vote(5, c5, n2); vote(6, c6, n1); vote(7, c7, n0);
#pragma unroll
        for (int k = 0; k < 2; ++k) { s_bi += flog2(pr[k]) + CLMP * zc[k]; }

        // ---- per-pixel tail ----
        const int tk[2] = {t2.x, t2.y};
#pragma unroll
        for (int k = 0; k < 2; ++k) {
            const float fm = vmax[k];
            s_bce += fmaxf(flog2(tk[k] ? fm : 1.f - fm), CLMP);
            const int sc = __popc((int)((lo >> (8 * k)) & 0xffu));
            s_dec += (sc > 0 && sc < 8) ? fmaxf(flog2(1.f - vmin[k]), CLMP) : 0.f;
            ci[k] += (float)tk[k];
            cj[k] += fm;
            cx[k] += tk[k] ? fm : 0.f;
        }

        // ---- rotate window ----
#pragma unroll
        for (int k = 0; k < 2; ++k) {
            C0[k] = F0[k]; C1[k] = F1[k]; C2[k] = F2[k];
            P5[k] = c5[k]; P6[k] = c6[k]; P7[k] = c7[k];
        }
    }

    // ---- dice partials: thread-exclusive columns, direct store ----
    if constexpr (SLAB) {
        const size_t sb = ((size_t)work) << 9;
        float2 vi; vi.x = ci[0]; vi.y = ci[1];
        float2 vj; vj.x = cj[0]; vj.y = cj[1];
        float2 vx; vx.x = cx[0]; vx.y = cx[1];
        *(float2*)(col_i + sb + wq) = vi;
        *(float2*)(col_j + sb + wq) = vj;
        *(float2*)(col_x + sb + wq) = vx;
    } else {
#pragma unroll
        for (int k = 0; k < 2; ++k) {
            atomicAdd(&col_i[b * Wn + wq + k], ci[k]);
            atomicAdd(&col_j[b * Wn + wq + k], cj[k]);
            atomicAdd(&col_x[b * Wn + wq + k], cx[k]);
        }
    }

    // ---- scalar sums: wave shuffle reduction ----
#pragma unroll
    for (int off = 32; off > 0; off >>= 1) {
        s_con += __shfl_down(s_con, off);
        s_bi  += __shfl_down(s_bi,  off);
        s_bce += __shfl_down(s_bce, off);
        s_dec += __shfl_down(s_dec, off);
    }
    __shared__ float wred[4][4];
    if (lane == 0) {   // convert log2 -> ln units here (one mul per sum)
        wred[wv][0] = s_con * LN2; wred[wv][1] = s_bi * LN2;
        wred[wv][2] = s_bce * LN2; wred[wv][3] = s_dec * LN2;
    }
    __syncthreads();
    if (tid < 4) {
        bscal[(size_t)work * 4 + tid] =
            (double)(wred[0][tid] + wred[1][tid] + wred[2][tid] + wred[3][tid]);
    }
}

// Slab finisher: 256 blocks x 256 threads. Block bx owns 32 columns; each
// column's 128 gx-partials are summed by 8 threads (16 each) -> LDS -> lane.
__global__ __launch_bounds__(256) void bicon_finish_slab(
    const float* __restrict__ pI,
    const float* __restrict__ pJ,
    const float* __restrict__ pX,
    const double* __restrict__ bscal,
    float* __restrict__ out)
{
    const int tid = threadIdx.x;
    const int w32 = tid & 31;                 // which of the block's 32 columns
    const int p   = tid >> 5;                 // gx partition 0..7 (16 gx each)
    const int col = blockIdx.x * 32 + w32;    // 0..8191
    const int b   = col >> 9;
    const int w   = col & 511;

    float fi = 0.f, fj = 0.f, fx = 0.f;
    const size_t base = (((size_t)(b * GX + p * 16)) << 9) + w;
#pragma unroll
    for (int g = 0; g < 16; ++g) {
        const size_t idx = base + ((size_t)g << 9);
        fi += pI[idx]; fj += pJ[idx]; fx += pX[idx];
    }
    __shared__ float red[3][8][32];           // 3 KB
    red[0][p][w32] = fi; red[1][p][w32] = fj; red[2][p][w32] = fx;
    __syncthreads();

    double part = 0.0;
    if (tid < 32) {                           // dice term for 32 columns
        float si = 0.f, sj = 0.f, sx = 0.f;
#pragma unroll
        for (int q = 0; q < 8; ++q) {
            si += red[0][q][tid]; sj += red[1][q][tid]; sx += red[2][q][tid];
        }
        part = (1.0 - (2.0 * (double)sx + 0.001) /
                      ((double)si + (double)sj + 0.001)) / 8192.0;
    }
    if (tid >= 64 && tid < 72) {              // 8 bscal slots, on wave 1
        const int s = blockIdx.x * 8 + (tid - 64);
        const double c0 = bscal[s * 4 + 0], c1 = bscal[s * 4 + 1];
        const double c2 = bscal[s * 4 + 2], c3 = bscal[s * 4 + 3];
        part += -0.8 * c0 / 33554432.0 - 0.2 * c1 / 33554432.0
                - c2 / 4194304.0 - c3 / 4194304.0;
    }
#pragma unroll
    for (int off = 32; off > 0; off >>= 1) part += __shfl_down(part, off);
    __shared__ double red2[4];
    if ((tid & 63) == 0) red2[tid >> 6] = part;
    __syncthreads();
    if (tid == 0) atomicAdd(out, (float)(red2[0] + red2[1] + red2[2] + red2[3]));
}

// Fallback finisher (atomic path): cols already reduced, 32 blocks suffice.
__global__ __launch_bounds__(256) void bicon_finish(
    const float* __restrict__ col_i,
    const float* __restrict__ col_j,
    const float* __restrict__ col_x,
    const double* __restrict__ bscal,
    float* __restrict__ out)
{
    const int tid = threadIdx.x;
    const int col = blockIdx.x * 256 + tid;      // exactly NCOL threads total

    double part;
    {
        const float fi = col_i[col], fj = col_j[col], fx = col_x[col];
        part = (1.0 - (2.0 * (double)fx + 0.001) /
                      ((double)fi + (double)fj + 0.001)) / 8192.0;
    }
    if (tid < 64) {   // 64 bscal slots per block: 32 blocks * 64 = 2048 = NBLK
        const int s = blockIdx.x * 64 + tid;
        const double c0 = bscal[s * 4 + 0], c1 = bscal[s * 4 + 1];
        const double c2 = bscal[s * 4 + 2], c3 = bscal[s * 4 + 3];
        part += -0.8 * c0 / 33554432.0 - 0.2 * c1 / 33554432.0
                - c2 / 4194304.0 - c3 / 4194304.0;
    }
#pragma unroll
    for (int off = 32; off > 0; off >>= 1) part += __shfl_down(part, off);
    __shared__ double red[4];
    if ((tid & 63) == 0) red[tid >> 6] = part;
    __syncthreads();
    if (tid == 0) atomicAdd(out, (float)(red[0] + red[1] + red[2] + red[3]));
}

extern "C" void kernel_launch(void* const* d_in, const int* in_sizes, int n_in,
                              void* d_out, int out_size, void* d_ws, size_t ws_size,
                              hipStream_t stream) {
    const float* c_map      = (const float*)d_in[0];
    const int*   target     = (const int*)d_in[1];
    const int*   con_target = (const int*)d_in[2];
    float* out = (float*)d_out;

    char* ws = (char*)d_ws;
    const size_t slab_need = (size_t)3 * SLABN * sizeof(float)
                           + (size_t)NBLK * 4 * sizeof(double);   // ~12.65 MB

    dim3 grid(GX, Bn);       // 128 x 16 = 2048 blocks
    dim3 block(256);

    hipMemsetAsync(d_out, 0, sizeof(float), stream);  // finisher atomics here

    if (ws_size >= slab_need) {
        float*  pI    = (float*)ws;                   // 2048 x 512 partials
        float*  pJ    = pI + SLABN;
        float*  pX    = pJ + SLABN;
        double* bscal = (double*)(ws + (size_t)3 * SLABN * sizeof(float));
        // no col memset needed: slabs are fully written
        bicon_main<true><<<grid, block, 0, stream>>>(c_map, target, con_target,
                                                     pI, pJ, pX, bscal);
        bicon_finish_slab<<<FBLK2, 256, 0, stream>>>(pI, pJ, pX, bscal, out);
    } else {
        float*  col_i = (float*)ws;                               // 8192 floats
        float*  col_j = col_i + NCOL;
        float*  col_x = col_j + NCOL;
        double* bscal = (double*)(ws + 3 * NCOL * sizeof(float)); // 2048*4 doubles
        hipMemsetAsync(d_ws, 0, 3 * NCOL * sizeof(float), stream);
        bicon_main<false><<<grid, block, 0, stream>>>(c_map, target, con_target,
                                                      col_i, col_j, col_x, bscal);
        bicon_finish<<<FBLK, 256, 0, stream>>>(col_i, col_j, col_x, bscal, out);
    }
}